// Round 12
// baseline (484.546 us; speedup 1.0000x reference)
//
#include <hip/hip_runtime.h>
#include <hip/hip_bf16.h>

typedef __attribute__((ext_vector_type(8))) short short8;
typedef __attribute__((ext_vector_type(4))) float floatx4;

__device__ __forceinline__ ushort f2bf(float x) {
    __hip_bfloat16 h = __float2bfloat16(x);
    return __builtin_bit_cast(ushort, h);
}
__device__ __forceinline__ float bf2f(ushort u) {
    __hip_bfloat16 h = __builtin_bit_cast(__hip_bfloat16, u);
    return __bfloat162float(h);
}

// fast tanh: 1 - 2/(e^{2z}+1); v_exp + v_rcp, ~1e-6 abs err
__device__ __forceinline__ float fast_tanh(float z) {
    float e = __expf(2.0f * z);
    return 1.0f - 2.0f * __builtin_amdgcn_rcpf(e + 1.0f);
}

// async global -> LDS, 16 bytes per lane. LDS dest is wave-uniform base + lane*16;
// per-lane GLOBAL source is arbitrary (exploited for the XOR bank swizzle).
__device__ __forceinline__ void gload_lds16(const ushort* g, ushort* l) {
    __builtin_amdgcn_global_load_lds(
        (const __attribute__((address_space(1))) unsigned int*)(const void*)g,
        (__attribute__((address_space(3))) unsigned int*)(void*)l,
        16, 0, 0);
}

// ---------------------------------------------------------------------------
// Fused prep, ONE dispatch, 18944 blocks x 256 threads.  (R11 measured, kept)
// ---------------------------------------------------------------------------
__global__ void prep(const float* __restrict__ inp, const float* __restrict__ hz,
                     const float* __restrict__ Wf, const float* __restrict__ W1,
                     const float* __restrict__ W2,
                     ushort* __restrict__ h0, ushort* __restrict__ WfT,
                     ushort* __restrict__ W1T, ushort* __restrict__ W2T) {
    int bid = blockIdx.x;
    int tid = threadIdx.x;
    __shared__ float tile[32][33];
    if (bid < 16384) {
        int u = bid * 256 + tid;
        const int isHz = (u >= 2097152) ? 1 : 0;
        const float* src = isHz ? hz : inp;
        const int v = u - isHz * 2097152;
        const size_t i = (size_t)v * 8;
        const size_t row = i >> 9;
        const int col = (int)(i & 511);
        float4 x0 = *(const float4*)(src + i);
        float4 x1 = *(const float4*)(src + i + 4);
        short8 o;
        o[0] = (short)f2bf(x0.x); o[1] = (short)f2bf(x0.y);
        o[2] = (short)f2bf(x0.z); o[3] = (short)f2bf(x0.w);
        o[4] = (short)f2bf(x1.x); o[5] = (short)f2bf(x1.y);
        o[6] = (short)f2bf(x1.z); o[7] = (short)f2bf(x1.w);
        *(short8*)(h0 + row * 1024 + isHz * 512 + col) = o;
    } else {
        int t = bid - 16384;
        const float* W;
        ushort* WT;
        int N = 1024;
        if (t < 1024)      { W = Wf; WT = WfT; }
        else if (t < 2048) { W = W1; WT = W1T; t -= 1024; }
        else               { W = W2; WT = W2T; t -= 2048; N = 512; }
        const int tx = tid & 31, ty = tid >> 5;
        const int nb = (t % (N / 32)) * 32, kb = (t / (N / 32)) * 32;
        #pragma unroll
        for (int j = ty; j < 32; j += 8)
            tile[j][tx] = W[(size_t)(kb + j) * N + nb + tx];
        __syncthreads();
        const int j2 = tid >> 3;
        const int kc = (tid & 7) * 4;
        ushort4 o = make_ushort4(f2bf(tile[kc][j2]),     f2bf(tile[kc + 1][j2]),
                                 f2bf(tile[kc + 2][j2]), f2bf(tile[kc + 3][j2]));
        *(ushort4*)(WT + (size_t)(nb + j2) * 1024 + kb + kc) = o;
    }
}

// ---------------------------------------------------------------------------
// 128x128-tile bf16 MFMA GEMM, 256 threads / 4 waves (2M x 2N), per-wave
// 64x64 output (acc[4][4] = 64 AGPR). BK=32, ring-2 LDS (32 KB total).
//
// OCCUPANCY REDESIGN (this round): halve per-wave register state (256 -> ~120
// unified) and LDS (128 KB -> 32 KB) so 3-4 blocks co-reside per CU
// (9-16 waves/CU vs 8). Schedule is the SIMPLE m97 2-phase loop:
//     STAGE(t+1) -> frag reads + 16 MFMA -> __syncthreads()
// One barrier per iter. __syncthreads() drains vmcnt(0)+lgkmcnt(0):
//  - availability: STAGE(t+1) issued by all waves before barrier(t); the
//    drain retires them -> slot (t+1)&1 valid at iter t+1.
//  - slot reuse: STAGE(t+2) at iter t+1 overwrites slot t&1; every wave's
//    iter-t ds_reads retired before it reached barrier(t).
// Cross-block TLP (m97/m114 mechanism) covers the per-iter drain stall —
// no source-level pipelining (measured to regress, R8).
//
// MODE 1: out_bf = bf2f(A[row][col]) + 0.1*tanh(acc + bias)   (euler step)
// MODE 2: out_bf = relu(acc + bias)
// MODE 3: out_f32 = tanh(acc + bias)
// Grid 1-D: xcd=id&7 owns 32 M-tiles; N-tiles innermost (A L2-reuse).
// ---------------------------------------------------------------------------
template <int MODE, int NOUT, int NX>
__global__ __launch_bounds__(256, 3) void gemm_ep(
    const ushort* __restrict__ A, const ushort* __restrict__ BT,
    const float* __restrict__ bias,
    ushort* __restrict__ outB, float* __restrict__ outF) {
    constexpr int K = 1024;
    constexpr int NT = 32;               // 32 k-panels of 32
    __shared__ ushort As[2][4096];       // 2 slots x 128 rows x 32 k = 16 KB
    __shared__ ushort Bs[2][4096];       // 16 KB

    const int tid = threadIdx.x;
    const int wave = tid >> 6, lane = tid & 63;

    const int id = blockIdx.x;
    const int inner = id >> 3;
    const int nTile = inner % NX;
    const int mTile = (id & 7) * 32 + inner / NX;   // 256 M-tiles / 8 XCDs
    const int mBase = mTile * 128;
    const int nBase = nTile * 128;
    const int waveM = wave >> 1;      // 0..1  (64-row band)
    const int waveN = wave & 1;       // 0..1  (64-col band)

    // Staging (measured-zero-conflict XOR layout): physical 16B slot c holds
    // logical (row r=c>>2, quad q=(c&3)^((r>>1)&3)); 512 slots per panel,
    // 2 sweeps of 256 threads.
    const int c0 = tid, c1 = tid + 256;
    const int ra0 = c0 >> 2, ra1 = c1 >> 2;
    const int qa0 = (c0 & 3) ^ ((ra0 >> 1) & 3);
    const int qa1 = (c1 & 3) ^ ((ra1 >> 1) & 3);
    const ushort* agA_0 = A  + (size_t)(mBase + ra0) * K + qa0 * 8;
    const ushort* agA_1 = A  + (size_t)(mBase + ra1) * K + qa1 * 8;
    const ushort* bgB_0 = BT + (size_t)(nBase + ra0) * K + qa0 * 8;
    const ushort* bgB_1 = BT + (size_t)(nBase + ra1) * K + qa1 * 8;

    floatx4 acc[4][4];
    #pragma unroll
    for (int i = 0; i < 4; i++)
        #pragma unroll
        for (int j = 0; j < 4; j++) acc[i][j] = (floatx4)(0.f);

    const int mrow = lane & 15;
    const int g = lane >> 4;                  // logical k-quad
    const int pq = g ^ ((mrow >> 1) & 3);     // physical quad (uniform across
                                              // frag offsets: multiples of 32)
    const ushort* aB = &As[0][0] + (waveM * 64 + mrow) * 32 + pq * 8;
    const ushort* bB = &Bs[0][0] + (waveN * 64 + mrow) * 32 + pq * 8;

#define STAGE(T)                                                        \
    {                                                                   \
        const int s_ = (T) & 1;                                         \
        gload_lds16(agA_0 + (T) * 32, &As[s_][0] + tid * 8);            \
        gload_lds16(agA_1 + (T) * 32, &As[s_][0] + (tid + 256) * 8);    \
        gload_lds16(bgB_0 + (T) * 32, &Bs[s_][0] + tid * 8);            \
        gload_lds16(bgB_1 + (T) * 32, &Bs[s_][0] + (tid + 256) * 8);    \
    }

    // prologue: stage panel 0; syncthreads drains vmcnt -> panel 0 ready
    STAGE(0)
    __syncthreads();

    #pragma unroll 4
    for (int t = 0; t < NT; ++t) {
        const int s = t & 1;
        if (t + 1 < NT) STAGE(t + 1)          // -> slot (t+1)&1 (= slot t-1)
        short8 af[4], bfr[4];
        #pragma unroll
        for (int i = 0; i < 4; i++) {
            af[i]  = *(const short8*)(aB + s * 4096 + i * 512);
            bfr[i] = *(const short8*)(bB + s * 4096 + i * 512);
        }
        __builtin_amdgcn_s_setprio(1);
        #pragma unroll
        for (int mt = 0; mt < 4; mt++)
            #pragma unroll
            for (int nt = 0; nt < 4; nt++)
                acc[mt][nt] = __builtin_amdgcn_mfma_f32_16x16x32_bf16(
                    af[mt], bfr[nt], acc[mt][nt], 0, 0, 0);
        __builtin_amdgcn_s_setprio(0);
        __syncthreads();                      // drains vmcnt+lgkm, then barrier
    }
#undef STAGE

    // epilogue: C/D layout col=lane&15, row=(lane>>4)*4+reg  [m89/m91]
    const int col0 = nBase + waveN * 64 + (lane & 15);
    const int row0 = mBase + waveM * 64 + (lane >> 4) * 4;
    #pragma unroll
    for (int mt = 0; mt < 4; mt++) {
        #pragma unroll
        for (int nt = 0; nt < 4; nt++) {
            const int col = col0 + nt * 16;
            const float bv = bias[col];
            #pragma unroll
            for (int r = 0; r < 4; r++) {
                const int row = row0 + mt * 16 + r;
                const float z = acc[mt][nt][r] + bv;
                if (MODE == 1) {
                    float carry = bf2f(A[(size_t)row * K + col]);
                    outB[(size_t)row * NOUT + col] = f2bf(carry + 0.1f * fast_tanh(z));
                } else if (MODE == 2) {
                    outB[(size_t)row * NOUT + col] = f2bf(fmaxf(z, 0.f));
                } else {
                    outF[(size_t)row * NOUT + col] = fast_tanh(z);
                }
            }
        }
    }
}

extern "C" void kernel_launch(void* const* d_in, const int* in_sizes, int n_in,
                              void* d_out, int out_size, void* d_ws, size_t ws_size,
                              hipStream_t stream) {
    const float* inp = (const float*)d_in[0];  // [32,1024,512]
    const float* hz  = (const float*)d_in[1];  // [32,1024,512]
    const float* Wf  = (const float*)d_in[2];  // [1024,1024]
    const float* bf_ = (const float*)d_in[3];  // [1024]
    const float* W1  = (const float*)d_in[4];  // [1024,1024]
    const float* b1  = (const float*)d_in[5];  // [1024]
    const float* W2  = (const float*)d_in[6];  // [1024,512]
    const float* b2  = (const float*)d_in[7];  // [512]
    float* out = (float*)d_out;                // [32,1024,512] fp32

    char* ws = (char*)d_ws;
    ushort* WfT  = (ushort*)(ws);                                  // 2 MB
    ushort* W1T  = (ushort*)(ws + (size_t)(2 << 20));              // 2 MB
    ushort* W2T  = (ushort*)(ws + (size_t)(4 << 20));              // 1 MB
    ushort* bufA = (ushort*)(ws + (size_t)(8 << 20));              // 64 MB
    ushort* bufB = (ushort*)(ws + (size_t)(8 << 20) + ((size_t)64 << 20));  // 64 MB

    // fused prep: h0 pack (16384 blocks) + 3 weight transposes (2560 blocks)
    prep<<<18944, 256, 0, stream>>>(inp, hz, Wf, W1, W2, bufA, WfT, W1T, W2T);

    // h1 = h0 + 0.1*tanh(h0@Wf + bf)      (256 M-tiles x 8 N-tiles)
    gemm_ep<1, 1024, 8><<<2048, 256, 0, stream>>>(bufA, WfT, bf_, bufB, nullptr);
    // h2 = h1 + 0.1*tanh(h1@Wf + bf)
    gemm_ep<1, 1024, 8><<<2048, 256, 0, stream>>>(bufB, WfT, bf_, bufA, nullptr);
    // g = relu(h2@W1 + b1)
    gemm_ep<2, 1024, 8><<<2048, 256, 0, stream>>>(bufA, W1T, b1, bufB, nullptr);
    // out = tanh(g@W2 + b2)               (256 M-tiles x 4 N-tiles)
    gemm_ep<3, 512, 4><<<1024, 256, 0, stream>>>(bufB, W2T, b2, nullptr, out);
}